// Round 10
// baseline (884.142 us; speedup 1.0000x reference)
//
#include <hip/hip_runtime.h>
#include <math.h>

#define S_    1024
#define D_    512
#define DI_   1024
#define DS_   16
#define KC_   4
#define E_    8
#define DFF_  2048
#define NTOK  2048     // B*S
#define VOCAB 32000
#define NCHUNK 16
#define CHL    64      // S_/NCHUNK
#define NSLOT 4096     // NTOK*2

typedef unsigned short ushort;
typedef unsigned int   uint;
typedef __attribute__((ext_vector_type(8))) short short8;
typedef __attribute__((ext_vector_type(4))) float f32x4;

// ---- split-weights region layout (ushort units, per layer) ----
#define IN_US   0ull
#define INL_US  1048576ull
#define OUT_US  2097152ull
#define OUTL_US 2621440ull
#define W1_US   3145728ull
#define W1L_US  11534336ull
#define W2_US   19922944ull
#define W2L_US  28311552ull
#define LAYER_US 36700160ull
#define LM_US   73400320ull
// flat float4 segment bounds for k_split_all
#define IN4   262144
#define OUT4  393216
#define W14   2490368
#define L4    4587520
#define LM4   4096000
#define LMEND 13271040
#define TOT4  13279232

// ---------------- helpers ----------------
__device__ __forceinline__ float gelu_sig(float x){
  float u = x*(1.5957691216057308f + 0.07135481627f*x*x);
  return x / (1.0f + expf(-u));
}
__device__ __forceinline__ ushort f2bf_rnd(float f){
  uint u = __float_as_uint(f);
  return (ushort)((u + 0x8000u) >> 16);
}
__device__ __forceinline__ float bf2f(ushort h){
  return __uint_as_float(((uint)h) << 16);
}
__device__ __forceinline__ void split1(float f, ushort& h, ushort& l){
  h = f2bf_rnd(f);
  float fh = bf2f(h);
  l = (ushort)(__float_as_uint(f - fh) >> 16);
}
// async global->LDS 16B/lane; LDS dest = wave-uniform base + lane*16
__device__ __forceinline__ void gl16(void* lds, const void* g){
  __builtin_amdgcn_global_load_lds(
      (const __attribute__((address_space(1))) void*)g,
      (__attribute__((address_space(3))) void*)lds, 16, 0, 0);
}

// ---- ALL weight transforms in one kernel: hi/lo splits, lm bf16, negA ----
// layer-2 w1/w2 are consumed at NT=1 -> skip their lo writes
__global__ __launch_bounds__(256) void k_split_all(
    const float* __restrict__ in_w, const float* __restrict__ out_w,
    const float* __restrict__ w1, const float* __restrict__ w2,
    const float* __restrict__ lm, const float* __restrict__ Alog,
    ushort* __restrict__ wsp, float* __restrict__ negA){
  int g = blockIdx.x*256 + threadIdx.x;
  if (g >= TOT4) return;
  if (g < 2*L4){
    int l = (g < L4) ? 0 : 1;
    int r = g - l*L4;
    const float* src; size_t dh_off, dl_off;
    bool wlo = true;
    if (r < IN4){
      src = in_w + (size_t)l*1048576 + (size_t)r*4;
      dh_off = (size_t)l*LAYER_US + IN_US  + (size_t)r*4;
      dl_off = (size_t)l*LAYER_US + INL_US + (size_t)r*4;
    } else if (r < OUT4){
      int r2 = r - IN4;
      src = out_w + (size_t)l*524288 + (size_t)r2*4;
      dh_off = (size_t)l*LAYER_US + OUT_US  + (size_t)r2*4;
      dl_off = (size_t)l*LAYER_US + OUTL_US + (size_t)r2*4;
    } else if (r < W14){
      int r3 = r - OUT4;
      src = w1 + (size_t)l*8388608 + (size_t)r3*4;
      dh_off = (size_t)l*LAYER_US + W1_US  + (size_t)r3*4;
      dl_off = (size_t)l*LAYER_US + W1L_US + (size_t)r3*4;
      wlo = (l == 0);
    } else {
      int r4 = r - W14;
      src = w2 + (size_t)l*8388608 + (size_t)r4*4;
      dh_off = (size_t)l*LAYER_US + W2_US  + (size_t)r4*4;
      dl_off = (size_t)l*LAYER_US + W2L_US + (size_t)r4*4;
      wlo = (l == 0);
    }
    float4 v = *(const float4*)src;
    ushort h0,h1,h2,h3,l0,l1,l2,l3;
    split1(v.x,h0,l0); split1(v.y,h1,l1); split1(v.z,h2,l2); split1(v.w,h3,l3);
    *(uint2*)(wsp + dh_off) = make_uint2((uint)h0|((uint)h1<<16), (uint)h2|((uint)h3<<16));
    if (wlo)
      *(uint2*)(wsp + dl_off) = make_uint2((uint)l0|((uint)l1<<16), (uint)l2|((uint)l3<<16));
  } else if (g < LMEND){
    int r = g - 2*L4;
    float4 v = *(const float4*)(lm + (size_t)r*4);
    ushort h0 = f2bf_rnd(v.x), h1 = f2bf_rnd(v.y), h2 = f2bf_rnd(v.z), h3 = f2bf_rnd(v.w);
    *(uint2*)(wsp + LM_US + (size_t)r*4) = make_uint2((uint)h0|((uint)h1<<16), (uint)h2|((uint)h3<<16));
  } else {
    int r = g - LMEND;
    float4 v = *(const float4*)(Alog + (size_t)r*4);
    float4 o; o.x=-expf(v.x); o.y=-expf(v.y); o.z=-expf(v.z); o.w=-expf(v.w);
    *(float4*)(negA + (size_t)r*4) = o;
  }
}

// ------- fused embed + rmsnorm -> split (layer 0 entry) -------
__global__ __launch_bounds__(128) void k_embed_rms(const int* __restrict__ ids,
    const float* __restrict__ tok, const float* __restrict__ pos,
    const float* __restrict__ w, float* __restrict__ x,
    ushort* __restrict__ oh, ushort* __restrict__ ol){
  int t = blockIdx.x;
  int d4 = threadIdx.x << 2;
  int s  = t & (S_-1);
  int id = ids[t];
  float4 tv = *(const float4*)(tok + (size_t)id*D_ + d4);
  float4 pv = *(const float4*)(pos + (size_t)s*D_ + d4);
  float4 v; v.x=tv.x+pv.x; v.y=tv.y+pv.y; v.z=tv.z+pv.z; v.w=tv.w+pv.w;
  *(float4*)(x + (size_t)t*D_ + d4) = v;
  float ss = v.x*v.x + v.y*v.y + v.z*v.z + v.w*v.w;
  #pragma unroll
  for (int off=32; off>=1; off>>=1) ss += __shfl_down(ss, off);
  __shared__ float sred[2];
  if ((threadIdx.x & 63) == 0) sred[threadIdx.x >> 6] = ss;
  __syncthreads();
  float total = sred[0] + sred[1];
  float scale = 1.0f / sqrtf(total * (1.0f/D_) + 1e-6f);
  float4 wv = *(const float4*)(w + d4);
  float4 o; o.x=v.x*scale*wv.x; o.y=v.y*scale*wv.y; o.z=v.z*scale*wv.z; o.w=v.w*scale*wv.w;
  ushort h0,h1,h2,h3,l0,l1,l2,l3;
  split1(o.x,h0,l0); split1(o.y,h1,l1); split1(o.z,h2,l2); split1(o.w,h3,l3);
  *(uint2*)(oh + (size_t)t*D_ + d4) = make_uint2((uint)h0|((uint)h1<<16), (uint)h2|((uint)h3<<16));
  *(uint2*)(ol + (size_t)t*D_ + d4) = make_uint2((uint)l0|((uint)l1<<16), (uint)l2|((uint)l3<<16));
}

// ------- rmsnorm -> split hi/lo; optional fused "x += sum_ks(P3[slotA]+P3[slotB])" -------
template<int ADD>
__global__ __launch_bounds__(128) void k_rmsnorm_split(float* __restrict__ x,
    const float* __restrict__ P3, const int* __restrict__ slotmap,
    const float* __restrict__ w, ushort* __restrict__ oh, ushort* __restrict__ ol){
  int t = blockIdx.x;
  int d4 = threadIdx.x << 2;
  float4 v = *(const float4*)(x + (size_t)t*D_ + d4);
  if (ADD){
    int s0 = slotmap[2*t], s1 = slotmap[2*t+1];
    #pragma unroll
    for (int ks=0; ks<4; ++ks){
      float4 p0 = *(const float4*)(P3 + ((size_t)ks*NSLOT + s0)*D_ + d4);
      float4 p1 = *(const float4*)(P3 + ((size_t)ks*NSLOT + s1)*D_ + d4);
      v.x += p0.x + p1.x; v.y += p0.y + p1.y; v.z += p0.z + p1.z; v.w += p0.w + p1.w;
    }
    *(float4*)(x + (size_t)t*D_ + d4) = v;
  }
  float ss = v.x*v.x + v.y*v.y + v.z*v.z + v.w*v.w;
  #pragma unroll
  for (int off=32; off>=1; off>>=1) ss += __shfl_down(ss, off);
  __shared__ float sred[2];
  if ((threadIdx.x & 63) == 0) sred[threadIdx.x >> 6] = ss;
  __syncthreads();
  float total = sred[0] + sred[1];
  float scale = 1.0f / sqrtf(total * (1.0f/D_) + 1e-6f);
  float4 wv = *(const float4*)(w + d4);
  float4 o; o.x=v.x*scale*wv.x; o.y=v.y*scale*wv.y; o.z=v.z*scale*wv.z; o.w=v.w*scale*wv.w;
  ushort h0,h1,h2,h3,l0,l1,l2,l3;
  split1(o.x,h0,l0); split1(o.y,h1,l1); split1(o.z,h2,l2); split1(o.w,h3,l3);
  *(uint2*)(oh + (size_t)t*D_ + d4) = make_uint2((uint)h0|((uint)h1<<16), (uint)h2|((uint)h3<<16));
  *(uint2*)(ol + (size_t)t*D_ + d4) = make_uint2((uint)l0|((uint)l1<<16), (uint)l2|((uint)l3<<16));
}

// ------- fused: x += sum_ks P2; rmsnorm -> split; router probs/top2 -------
__global__ __launch_bounds__(128) void k_rmsnorm_router(float* __restrict__ x,
    const float* __restrict__ P2, const float* __restrict__ w,
    const float* __restrict__ rw, const float* __restrict__ rb,
    ushort* __restrict__ oh, ushort* __restrict__ ol,
    float* __restrict__ probs, float* __restrict__ topw, int* __restrict__ topi){
  int t = blockIdx.x;
  int tid = threadIdx.x;
  int d4 = tid << 2;
  float4 v = *(const float4*)(x + (size_t)t*D_ + d4);
  #pragma unroll
  for (int ks=0; ks<4; ++ks){
    float4 p = *(const float4*)(P2 + (size_t)ks*NTOK*D_ + (size_t)t*D_ + d4);
    v.x += p.x; v.y += p.y; v.z += p.z; v.w += p.w;
  }
  *(float4*)(x + (size_t)t*D_ + d4) = v;
  float ss = v.x*v.x + v.y*v.y + v.z*v.z + v.w*v.w;
  #pragma unroll
  for (int off=32; off>=1; off>>=1) ss += __shfl_down(ss, off);
  __shared__ float sred[2];
  __shared__ float lg2[2][E_];
  __shared__ float lg[E_];
  if ((tid & 63) == 0) sred[tid >> 6] = ss;
  __syncthreads();
  float total = sred[0] + sred[1];
  float scale = 1.0f / sqrtf(total * (1.0f/D_) + 1e-6f);
  float4 wv = *(const float4*)(w + d4);
  float4 o; o.x=v.x*scale*wv.x; o.y=v.y*scale*wv.y; o.z=v.z*scale*wv.z; o.w=v.w*scale*wv.w;
  ushort h0,h1,h2,h3,l0,l1,l2,l3;
  split1(o.x,h0,l0); split1(o.y,h1,l1); split1(o.z,h2,l2); split1(o.w,h3,l3);
  *(uint2*)(oh + (size_t)t*D_ + d4) = make_uint2((uint)h0|((uint)h1<<16), (uint)h2|((uint)h3<<16));
  *(uint2*)(ol + (size_t)t*D_ + d4) = make_uint2((uint)l0|((uint)l1<<16), (uint)l2|((uint)l3<<16));
  int lane = tid & 63, wid2 = tid >> 6;
  #pragma unroll
  for (int e=0;e<E_;e++){
    const float* rr = rw + (size_t)e*D_ + d4;
    float p = o.x*rr[0] + o.y*rr[1] + o.z*rr[2] + o.w*rr[3];
    #pragma unroll
    for (int off=32; off>=1; off>>=1) p += __shfl_down(p, off);
    if (lane==0) lg2[wid2][e] = p;
  }
  __syncthreads();
  if (tid==0){
    #pragma unroll
    for (int e=0;e<E_;e++) lg[e] = lg2[0][e] + lg2[1][e] + rb[e];
    float mx = lg[0];
    #pragma unroll
    for (int e=1;e<E_;e++) mx = fmaxf(mx, lg[e]);
    float pe[E_]; float sum = 0.f;
    #pragma unroll
    for (int e=0;e<E_;e++){ pe[e] = expf(lg[e]-mx); sum += pe[e]; }
    #pragma unroll
    for (int e=0;e<E_;e++){ pe[e] /= sum; probs[(size_t)t*E_ + e] = pe[e]; }
    int i1 = 0;
    #pragma unroll
    for (int e=1;e<E_;e++) if (pe[e] > pe[i1]) i1 = e;
    int i2 = (i1==0) ? 1 : 0;
    #pragma unroll
    for (int e=0;e<E_;e++) if (e!=i1 && pe[e] > pe[i2]) i2 = e;
    float wsum = pe[i1] + pe[i2];
    topw[t*2]   = pe[i1]/wsum;
    topw[t*2+1] = pe[i2]/wsum;
    topi[t*2] = i1; topi[t*2+1] = i2;
  }
}

// ============ split-bf16 MFMA GEMM, global_load_lds staging ============
// Row tile MT (64 or 128) x 128 cols. LDS [rows][32 us] unpadded; 16B chunk g of
// row r stored at phys g^((r>>1)&3) (2-way-only bank aliasing on b128 reads).
template<int EPI, int NT, int KSP, int MT>
__global__ __launch_bounds__(256, 4) void gemm_mfma(
    const ushort* __restrict__ Ahg, const ushort* __restrict__ Alg,
    const ushort* __restrict__ Whb, const ushort* __restrict__ Wlb,
    float* __restrict__ Cb, ushort* __restrict__ Chh, ushort* __restrict__ Chl,
    const float* __restrict__ biasb, const float* __restrict__ slotw,
    const int* __restrict__ gidx, const int* __restrict__ offs,
    int M, int N, int K)
{
  constexpr int MI  = MT/32;    // acc rows (A frags per wave)
  constexpr int AG  = MT/64;    // A staging groups per wave (1 or 2)
  constexpr int RPW = MT/4;     // A rows staged per wave
  int e, ksp;
  if (KSP > 1){ e = blockIdx.z / KSP; ksp = blockIdx.z % KSP; }
  else        { e = blockIdx.z;       ksp = 0; }
  int off = 0, cnt = M;
  if (EPI==1 || EPI==3){
    off = offs[e];
    cnt = offs[e+1] - off;
    if ((int)(blockIdx.x*MT) >= cnt) return;
  }
  const size_t wbase = (size_t)((EPI==1||EPI==3) ? e : 0) * N * K;
  const ushort* Whg = Whb + wbase;
  const ushort* Wlg = Wlb + wbase;
  const float* bias = (EPI==1||EPI==3) ? (biasb + (size_t)e * N) : biasb;

  __shared__ ushort sAh[MT*32];
  __shared__ ushort sWh[128*32];
  __shared__ ushort sAl[(NT>1)?(MT*32):8];
  __shared__ ushort sWl[(NT>1)?(128*32):8];

  const int tid  = threadIdx.x;
  const int row0 = blockIdx.x * MT;
  const int col0 = blockIdx.y * 128;
  const int lane = tid & 63;
  const int wid  = tid >> 6;

  // ---- staging: wave wid stages A rows [wid*RPW,+RPW), W rows [wid*32,+32) ----
  const int schunk = (lane&3) ^ ((lane>>3)&3);   // (r>>1)&3 pre-swizzle
  const int arow_b = wid*RPW + (lane>>2);
  const int wrow_b = wid*32  + (lane>>2);

  const int k0 = ksp * (K / KSP);
  const int nk = K / KSP;

  const ushort* gah[2]; const ushort* gal[2];
  #pragma unroll
  for (int s=0; s<AG; ++s){
    int lrr = row0 + arow_b + s*16;
    int ar;
    if (EPI==1){ if (lrr > cnt-1) lrr = cnt-1; ar = gidx[off + lrr]; }
    else if (EPI==3){ if (lrr > cnt-1) lrr = cnt-1; ar = off + lrr; }
    else ar = lrr;
    gah[s] = Ahg + (size_t)ar*K + k0 + schunk*8;
    if (NT>1) gal[s] = Alg + (size_t)ar*K + k0 + schunk*8;
  }
  const ushort* gwh[2]; const ushort* gwl[2];
  #pragma unroll
  for (int s=0; s<2; ++s){
    int wr = col0 + wrow_b + s*16;
    gwh[s] = Whg + (size_t)wr*K + k0 + schunk*8;
    if (NT>1) gwl[s] = Wlg + (size_t)wr*K + k0 + schunk*8;
  }

  // ---- fragment read geometry ----
  const int lr  = lane & 15;
  const int kq  = lane >> 4;
  const int kx  = ((kq ^ ((lr>>1)&3)) << 3);
  const int wrM = (wid >> 1) * (MT/2);
  const int wcN = (wid & 1) * 64;

  f32x4 zero = {0.f, 0.f, 0.f, 0.f};
  f32x4 acc[MI][4];
  #pragma unroll
  for (int i=0;i<MI;i++)
    #pragma unroll
    for (int j=0;j<4;j++) acc[i][j] = zero;

  for (int kk=0; kk<nk; kk+=32){
    __syncthreads();
    #pragma unroll
    for (int s=0; s<AG; ++s)
      gl16(&sAh[(wid*RPW + s*16)*32], gah[s] + kk);
    #pragma unroll
    for (int s=0; s<2; ++s)
      gl16(&sWh[(wid*32 + s*16)*32], gwh[s] + kk);
    if (NT>1){
      #pragma unroll
      for (int s=0; s<AG; ++s)
        gl16(&sAl[(wid*RPW + s*16)*32], gal[s] + kk);
      #pragma unroll
      for (int s=0; s<2; ++s)
        gl16(&sWl[(wid*32 + s*16)*32], gwl[s] + kk);
    }
    __syncthreads();

    short8 fah[MI], fal[MI], fbh[4], fbl[4];
    #pragma unroll
    for (int f=0; f<MI; ++f){
      int rA = wrM + f*16 + lr;
      fah[f] = *(const short8*)&sAh[rA*32 + kx];
      if (NT>1) fal[f] = *(const short8*)&sAl[rA*32 + kx];
    }
    #pragma unroll
    for (int f=0; f<4; ++f){
      int rB = wcN + f*16 + lr;
      fbh[f] = *(const short8*)&sWh[rB*32 + kx];
      if (NT>1) fbl[f] = *(const short8*)&sWl[rB*32 + kx];
    }
    #pragma unroll
    for (int i=0;i<MI;i++)
      #pragma unroll
      for (int j=0;j<4;j++){
        f32x4 c = acc[i][j];
        if (NT==4) c = __builtin_amdgcn_mfma_f32_16x16x32_bf16(fal[i], fbl[j], c, 0,0,0);
        if (NT>1){
          c = __builtin_amdgcn_mfma_f32_16x16x32_bf16(fal[i], fbh[j], c, 0,0,0);
          c = __builtin_amdgcn_mfma_f32_16x16x32_bf16(fah[i], fbl[j], c, 0,0,0);
        }
        c = __builtin_amdgcn_mfma_f32_16x16x32_bf16(fah[i], fbh[j], c, 0,0,0);
        acc[i][j] = c;
      }
  }

  float bj[4];
  if (EPI==1 || EPI==3){
    #pragma unroll
    for (int j=0;j<4;j++) bj[j] = bias[col0 + wcN + j*16 + lr];
  }
  #pragma unroll
  for (int i=0;i<MI;i++){
    #pragma unroll
    for (int jj=0;jj<4;jj++){
      int rt   = wrM + i*16 + kq*4 + jj;
      int grow = row0 + rt;
      if (EPI==0){
        float* cr = Cb + (size_t)grow*N + col0 + wcN + lr;
        #pragma unroll
        for (int j=0;j<4;j++) cr[j*16] = acc[i][j][jj];
      } else if (EPI==2){
        float* cr = Cb + (size_t)ksp*M*N + (size_t)grow*N + col0 + wcN + lr;
        #pragma unroll
        for (int j=0;j<4;j++) cr[j*16] = acc[i][j][jj];
      } else if (EPI==1){
        if (grow < cnt){
          int slot = off + grow;
          size_t base = (size_t)slot*N + col0 + wcN + lr;
          #pragma unroll
          for (int j=0;j<4;j++){
            float g = gelu_sig(acc[i][j][jj] + bj[j]);
            ushort hh_ = f2bf_rnd(g);
            Chh[base + j*16] = hh_;
            if (NT>1){
              ushort ll_ = (ushort)(__float_as_uint(g - bf2f(hh_)) >> 16);
              Chl[base + j*16] = ll_;
            }
          }
        }
      } else {
        if (grow < cnt){
          int slot = off + grow;
          float sw = slotw[slot];
          float* cr = Cb + ((size_t)ksp*NSLOT + slot)*N + col0 + wcN + lr;
          #pragma unroll
          for (int j=0;j<4;j++){
            float v = acc[i][j][jj];
            if (ksp==0) v += bj[j];
            cr[j*16] = sw*v;
          }
        }
      }
    }
  }
}

// ============ lm_head: bf16 GEMM, 128x256 tile, global_load_lds ============
__global__ __launch_bounds__(256, 2) void gemm_lm(
    const ushort* __restrict__ Ahg, const ushort* __restrict__ Whg,
    float* __restrict__ Cb, int M, int N, int K)
{
  __shared__ ushort sAh[128*32];
  __shared__ ushort sWh[256*32];
  const int tid  = threadIdx.x;
  const int row0 = blockIdx.x * 128;
  const int col0 = blockIdx.y * 256;
  const int lane = tid & 63;
  const int wid  = tid >> 6;

  const int schunk = (lane&3) ^ ((lane>>3)&3);
  const int srowA  = wid*32 + (lane>>2);
  const int ldsA0  = (wid*32)*32;
  const int ldsA1  = (wid*32+16)*32;
  const ushort* ga0 = Ahg + (size_t)(row0 + srowA)*K + schunk*8;
  const ushort* ga1 = Ahg + (size_t)(row0 + srowA + 16)*K + schunk*8;

  const int srowW  = wid*64 + (lane>>2);
  const int ldsW0  = (wid*64)*32,    ldsW1 = (wid*64+16)*32;
  const int ldsW2  = (wid*64+32)*32, ldsW3 = (wid*64+48)*32;
  const ushort* gw0 = Whg + (size_t)(col0 + srowW)*K      + schunk*8;
  const ushort* gw1 = Whg + (size_t)(col0 + srowW + 16)*K + schunk*8;
  const ushort* gw2 = Whg + (size_t)(col0 + srowW + 32)*K + schunk*8;
  const ushort* gw3 = Whg + (size_t)(col0 + srowW + 48)*K + schunk*8;

  const int lr  = lane & 15;
  const int kq  = lane >> 4;
  const int kx  = ((kq ^ ((lr>>1)&3)) << 3);
  const int wrM = (wid >> 1) * 64;
  const int wcN = (wid & 1) * 128;

  f32x4 zero = {0.f, 0.f, 0.f, 0.f};
  f32x4 acc[4][8];
  #pragma unroll
  for (int i=0;i<4;i++)
    #pragma unroll
    for (int j=0;j<8;j++) acc[i][j] = zero;

  for (int kk=0; kk<K; kk+=32){
    __syncthreads();
    gl16(&sAh[ldsA0], ga0 + kk);
    gl16(&sAh[ldsA1], ga1 + kk);
    gl16(&sWh[ldsW0], gw0 + kk);
    gl16(&sWh[ldsW1], gw1 + kk);
    gl16(&sWh[ldsW2], gw2 + kk);
    gl16(&sWh[ldsW3], gw3 + kk);
    __syncthreads();

    short8 fa[4], fb[8];
    #pragma unroll
    for (int f=0; f<4; ++f)
      fa[f] = *(const short8*)&sAh[(wrM + f*16 + lr)*32 + kx];
    #pragma unroll
    for (int f=0; f<8; ++f)
      fb[f] = *(const short8*)&sWh[(wcN + f*16 + lr)*32 + kx];
    #pragma unroll
    for (int i=0;i<4;i++)
      #pragma unroll
      for (int j=0;j<8;j++)
        acc[i][j] = __builtin_amdgcn_mfma_f32_16x16x32_bf16(fa[i], fb[j], acc[i][j], 0,0,0);
  }

  #pragma unroll
  for (int i=0;i<4;i++){
    #pragma unroll
    for (int jj=0;jj<4;jj++){
      int grow = row0 + wrM + i*16 + kq*4 + jj;
      float* cr = Cb + (size_t)grow*N + col0 + wcN + lr;
      #pragma unroll
      for (int j=0;j<8;j++) cr[j*16] = acc[i][j][jj];
    }
  }
}

// ------ fused: conv(KC=4)+bias ; x_dbl (B,delta,sdb) ; a,b tensors ------
__global__ __launch_bounds__(256) void k_convab(const float* __restrict__ xz,
    const float* __restrict__ cw, const float* __restrict__ cb,
    const float* __restrict__ xpw, const float* __restrict__ dtw,
    const float* __restrict__ dtb, const float* __restrict__ negA,
    float* __restrict__ a, float* __restrict__ bb){
  int t = blockIdx.x;
  int b = t >> 10, s = t & (S_-1);
  int tid = threadIdx.x;
  int c0 = tid << 2;
  __shared__ float xrow[DI_];
  __shared__ float outv[32];
  __shared__ float dl[DS_+1];
  float4 acc = *(const float4*)(cb + c0);
  #pragma unroll
  for (int k=0;k<KC_;k++){
    int ss = s - (KC_-1) + k;
    if (ss >= 0){
      float4 xv = *(const float4*)(xz + ((size_t)(b*S_+ss))*(2*DI_) + c0);
      acc.x += xv.x * cw[(c0+0)*KC_ + k];
      acc.y += xv.y * cw[(c0+1)*KC_ + k];
      acc.z += xv.z * cw[(c0+2)*KC_ + k];
      acc.w += xv.w * cw[(c0+3)*KC_ + k];
    }
  }
  *(float4*)(xrow + c0) = acc;
  __syncthreads();
  int wid = tid >> 6, lane = tid & 63;
  #pragma unroll
  for (int oi=0; oi<8; ++oi){
    int o = wid*8 + oi;
    const float* wr = (o < 16) ? (xpw + (size_t)(DS_ + o)*DI_) : (dtw + (size_t)(o-16)*DI_);
    float sum = 0.f;
    #pragma unroll
    for (int j=0;j<16;j++) sum += xrow[lane + 64*j] * wr[lane + 64*j];
    #pragma unroll
    for (int off=32; off>=1; off>>=1) sum += __shfl_down(sum, off);
    if (lane == 0) outv[o] = sum;
  }
  __syncthreads();
  if (tid < DS_){
    float d  = outv[16+tid] + dtb[tid];
    float sp = fmaxf(d, 0.f) + log1pf(expf(-fabsf(d)));
    dl[tid] = sp;
    float pr = sp * outv[tid];
    #pragma unroll
    for (int off=8; off>=1; off>>=1) pr += __shfl_down(pr, off);
    if (tid == 0) dl[DS_] = pr;
  }
  __syncthreads();
  float sdbv = dl[DS_];
  float av[4];
  #pragma unroll
  for (int i=0;i<4;i++){
    const float* nA = negA + (size_t)(c0+i)*DS_;
    float sum = 0.f;
    #pragma unroll
    for (int ds=0; ds<DS_; ds++) sum += expf(dl[ds] * nA[ds]);
    av[i] = sum;
  }
  *(float4*)(a + (size_t)t*DI_ + c0) = make_float4(av[0],av[1],av[2],av[3]);
  float4 bv; bv.x=acc.x*sdbv; bv.y=acc.y*sdbv; bv.z=acc.z*sdbv; bv.w=acc.w*sdbv;
  *(float4*)(bb + (size_t)t*DI_ + c0) = bv;
}

__global__ __launch_bounds__(256) void k_scan1(const float* __restrict__ a,
    const float* __restrict__ bb, float* __restrict__ aprod, float* __restrict__ yend){
  int g  = blockIdx.x*256 + threadIdx.x;
  int di = g & (DI_-1);
  int c  = (g >> 10) & (NCHUNK-1);
  int b  = g >> 14;
  float ap = 1.f, y = 0.f;
  size_t base = ((size_t)b*S_ + (size_t)c*CHL)*DI_ + di;
  #pragma unroll 4
  for (int i=0;i<CHL;i++){
    float at = a[base + (size_t)i*DI_], bt = bb[base + (size_t)i*DI_];
    y = at*y + bt; ap *= at;
  }
  aprod[g] = ap; yend[g] = y;
}

__global__ __launch_bounds__(256) void k_scan2(const float* __restrict__ a,
    const float* __restrict__ bb, const float* __restrict__ xz,
    const float* __restrict__ aprod, const float* __restrict__ yend,
    ushort* __restrict__ yh, ushort* __restrict__ yl){
  int g  = blockIdx.x*256 + threadIdx.x;
  int di = g & (DI_-1);
  int c  = (g >> 10) & (NCHUNK-1);
  int b  = g >> 14;
  float y = 0.f;
  for (int j=0;j<c;j++){
    int gg = ((b*NCHUNK + j) << 10) + di;
    y = aprod[gg]*y + yend[gg];
  }
  size_t base = ((size_t)b*S_ + (size_t)c*CHL)*DI_ + di;
  #pragma unroll 4
  for (int i=0;i<CHL;i++){
    float at = a[base + (size_t)i*DI_], bt = bb[base + (size_t)i*DI_];
    y = at*y + bt;
    float z = xz[((size_t)(b*S_ + c*CHL + i))*(2*DI_) + DI_ + di];
    float sil = z / (1.f + expf(-z));
    float v = y * sil;
    ushort hh, ll; split1(v, hh, ll);
    yh[base + (size_t)i*DI_] = hh;
    yl[base + (size_t)i*DI_] = ll;
  }
}

// ------- compaction + aux, LDS-staged (single block, 8 warps = 8 experts) -------
__global__ __launch_bounds__(512) void k_compact_aux(const int* __restrict__ topi,
    const float* __restrict__ topw, const float* __restrict__ probs,
    int* __restrict__ gidx, float* __restrict__ asgw, int* __restrict__ slotmap,
    int* __restrict__ offs, float* __restrict__ dst, int first){
  int tid = threadIdx.x;
  int e = tid >> 6, lane = tid & 63;
  __shared__ unsigned char stop[NTOK*2];
  __shared__ float stw[NTOK*2];
  __shared__ int counts[E_];
  __shared__ float red[8][E_];
  for (int i = tid; i < NTOK*2; i += 512){
    stop[i] = (unsigned char)topi[i];
    stw[i]  = topw[i];
  }
  float ps[E_];
  #pragma unroll
  for (int q=0;q<E_;q++) ps[q]=0.f;
  for (int t = tid; t < NTOK; t += 512){
    float4 p0 = *(const float4*)(probs + (size_t)t*E_);
    float4 p1 = *(const float4*)(probs + (size_t)t*E_ + 4);
    ps[0]+=p0.x; ps[1]+=p0.y; ps[2]+=p0.z; ps[3]+=p0.w;
    ps[4]+=p1.x; ps[5]+=p1.y; ps[6]+=p1.z; ps[7]+=p1.w;
  }
  #pragma unroll
  for (int q=0;q<E_;q++){
    float v = ps[q];
    #pragma unroll
    for (int off=32; off>=1; off>>=1) v += __shfl_down(v, off);
    if (lane==0) red[e][q] = v;
  }
  __syncthreads();
  int cnt = 0;
  for (int c=0; c<NTOK/64; ++c){
    int t = c*64 + lane;
    bool flag = (stop[2*t]==e) || (stop[2*t+1]==e);
    unsigned long long m = __ballot(flag);
    cnt += __popcll(m);
  }
  if (lane==0) counts[e] = cnt;
  __syncthreads();
  int base = 0;
  for (int i=0;i<e;i++) base += counts[i];
  if (lane==0) offs[e] = base;
  if (tid==0){
    int tot=0;
    for (int i=0;i<E_;i++) tot += counts[i];
    offs[E_] = tot;
  }
  int run = base;
  for (int c=0; c<NTOK/64; ++c){
    int t = c*64 + lane;
    int which = (stop[2*t]==e) ? 0 : ((stop[2*t+1]==e) ? 1 : -1);
    bool flag = which >= 0;
    unsigned long long m = __ballot(flag);
    int rank = __popcll(m & ((1ull<<lane)-1ull));
    if (flag){
      int pos = run + rank;
      gidx[pos] = t;
      asgw[pos] = stw[2*t+which];
      slotmap[2*t+which] = pos;
    }
    run += __popcll(m);
  }
  if (tid==0){
    float aux = 0.f;
    #pragma unroll
    for (int i=0;i<E_;i++){
      float P = 0.f;
      #pragma unroll
      for (int wdd=0; wdd<8; ++wdd) P += red[wdd][i];
      P *= (1.0f/NTOK);
      float f = (float)counts[i] * (1.0f/(NTOK*2.0f));
      aux += f*P;
    }
    aux *= (float)E_;
    if (first) dst[0] = aux; else dst[0] += aux;
  }
}

// ---------------- host ----------------
extern "C" void kernel_launch(void* const* d_in, const int* in_sizes, int n_in,
                              void* d_out, int out_size, void* d_ws, size_t ws_size,
                              hipStream_t stream) {
  const int*   input_ids  = (const int*)  d_in[0];
  const float* tok_emb    = (const float*)d_in[1];
  const float* pos_emb    = (const float*)d_in[2];
  const float* norm1_w    = (const float*)d_in[3];
  const float* norm2_w    = (const float*)d_in[4];
  const float* in_proj_w  = (const float*)d_in[5];
  const float* conv_w     = (const float*)d_in[6];
  const float* conv_b     = (const float*)d_in[7];
  const float* x_proj_w   = (const float*)d_in[8];
  const float* dt_proj_w  = (const float*)d_in[9];
  const float* dt_proj_b  = (const float*)d_in[10];
  const float* A_log      = (const float*)d_in[11];
  const float* out_proj_w = (const float*)d_in[13];
  const float* router_w   = (const float*)d_in[14];
  const float* router_b   = (const float*)d_in[15];
  const float* w1         = (const float*)d_in[16];
  const float* b1         = (const float*)d_in[17];
  const float* w2         = (const float*)d_in[18];
  const float* b2         = (const float*)d_in[19];
  const float* final_norm = (const float*)d_in[20];
  const float* lm_head_w  = (const float*)d_in[21];
  float* out = (float*)d_out;

  float* f0 = (float*)d_ws;
  float*  x    = f0;
  ushort* xnh  = (ushort*)(f0 + 1048576);
  ushort* xnl  = xnh + 1048576;
  float*  xz   = f0 + 2097152;
  float*  a    = f0 + 6291456;
  float*  bb   = f0 + 8388608;
  ushort* yh   = (ushort*)(f0 + 10485760);
  ushort* yl   = yh + 2097152;
  ushort* hh   = (ushort*)(f0 + 12582912);
  ushort* hl   = hh + 8388608;
  float*  P2   = f0 + 20971520;
  float*  P3   = f0 + 25165824;
  ushort* wsplit = (ushort*)(f0 + 33554432);
  float*  negA = f0 + 78446592;
  float*  aprod= negA + 32768;
  float*  yendb= aprod + 32768;
  float*  probs= yendb + 32768;
  float*  topw = probs + 16384;
  float*  asgw = topw + 4096;
  int*    topi = (int*)(asgw + 4096);
  int*    gidx = topi + 4096;
  int*    slotmap = gidx + 4096;
  int*    offs = slotmap + 4096;

  float* aux_dst = out + (size_t)NTOK*VOCAB;

  k_split_all<<<(TOT4+255)/256, 256, 0, stream>>>(in_proj_w, out_proj_w, w1, w2,
                                                  lm_head_w, A_log, wsplit, negA);
  k_embed_rms<<<NTOK, 128, 0, stream>>>(input_ids, tok_emb, pos_emb, norm1_w, x, xnh, xnl);

  for (int l=0; l<2; ++l){
    ushort* L = wsplit + (size_t)l*LAYER_US;
    // ---- mamba ----
    if (l == 1)
      k_rmsnorm_split<1><<<NTOK, 128, 0, stream>>>(x, P3, slotmap,
          norm1_w + (size_t)l*D_, xnh, xnl);
    gemm_mfma<0,3,1,64><<<dim3(32,16,1), 256, 0, stream>>>(xnh, xnl, L+IN_US, L+INL_US,
        xz, nullptr, nullptr, nullptr, nullptr, nullptr, nullptr, NTOK, 2*DI_, D_);
    k_convab<<<NTOK, 256, 0, stream>>>(xz, conv_w + (size_t)l*DI_*KC_, conv_b + (size_t)l*DI_,
                                       x_proj_w + (size_t)l*2*DS_*DI_,
                                       dt_proj_w + (size_t)l*DS_*DI_, dt_proj_b + (size_t)l*DS_,
                                       negA + (size_t)l*DI_*DS_, a, bb);
    k_scan1<<<(NTOK*NCHUNK)/256, 256, 0, stream>>>(a, bb, aprod, yendb);
    k_scan2<<<(NTOK*NCHUNK)/256, 256, 0, stream>>>(a, bb, xz, aprod, yendb, yh, yl);
    gemm_mfma<2,3,4,64><<<dim3(32,4,4), 256, 0, stream>>>(yh, yl, L+OUT_US, L+OUTL_US,
        P2, nullptr, nullptr, nullptr, nullptr, nullptr, nullptr, NTOK, D_, DI_);
    // ---- moe (sparse top-2) ----
    k_rmsnorm_router<<<NTOK, 128, 0, stream>>>(x, P2, norm2_w + (size_t)l*D_,
        router_w + (size_t)l*E_*D_, router_b + (size_t)l*E_,
        xnh, xnl, probs, topw, topi);
    k_compact_aux<<<1, 512, 0, stream>>>(topi, topw, probs, gidx, asgw, slotmap, offs,
                                         aux_dst, l==0 ? 1 : 0);
    if (l == 0){
      gemm_mfma<1,3,1,64><<<dim3(32,16,8), 256, 0, stream>>>(xnh, xnl, L+W1_US, L+W1L_US,
          nullptr, hh, hl, b1 + (size_t)l*E_*DFF_, nullptr, gidx, offs, 0, DFF_, D_);
      gemm_mfma<3,3,4,64><<<dim3(32,4,32), 256, 0, stream>>>(hh, hl, L+W2_US, L+W2L_US,
          P3, nullptr, nullptr, b2 + (size_t)l*E_*D_, asgw, gidx, offs, 0, D_, DFF_);
    } else {
      gemm_mfma<1,1,1,64><<<dim3(32,16,8), 256, 0, stream>>>(xnh, nullptr, L+W1_US, nullptr,
          nullptr, hh, nullptr, b1 + (size_t)l*E_*DFF_, nullptr, gidx, offs, 0, DFF_, D_);
      gemm_mfma<3,1,4,64><<<dim3(32,4,32), 256, 0, stream>>>(hh, nullptr, L+W2_US, nullptr,
          P3, nullptr, nullptr, b2 + (size_t)l*E_*D_, asgw, gidx, offs, 0, D_, DFF_);
    }
  }

  // ---- head ----
  k_rmsnorm_split<1><<<NTOK, 128, 0, stream>>>(x, P3, slotmap, final_norm, xnh, xnl);
  gemm_lm<<<dim3(16,125,1), 256, 0, stream>>>(xnh, wsplit + LM_US, out, NTOK, VOCAB, D_);
}

// Round 11
// 828.358 us; speedup vs baseline: 1.0673x; 1.0673x over previous
//
#include <hip/hip_runtime.h>
#include <math.h>

#define S_    1024
#define D_    512
#define DI_   1024
#define DS_   16
#define KC_   4
#define E_    8
#define DFF_  2048
#define NTOK  2048     // B*S
#define VOCAB 32000
#define NCHUNK 16
#define CHL    64      // S_/NCHUNK
#define NSLOT 4096     // NTOK*2

typedef unsigned short ushort;
typedef unsigned int   uint;
typedef __attribute__((ext_vector_type(8))) short short8;
typedef __attribute__((ext_vector_type(4))) float f32x4;

// ---- split-weights region layout (ushort units, per layer) ----
#define IN_US   0ull
#define INL_US  1048576ull
#define OUT_US  2097152ull
#define OUTL_US 2621440ull
#define W1_US   3145728ull
#define W1L_US  11534336ull
#define W2_US   19922944ull
#define W2L_US  28311552ull
#define LAYER_US 36700160ull
#define LM_US   73400320ull
// flat float4 segment bounds for k_split_all
#define IN4   262144
#define OUT4  393216
#define W14   2490368
#define L4    4587520
#define LM4   4096000
#define LMEND 13271040
#define TOT4  13279232

// ---------------- helpers ----------------
__device__ __forceinline__ float gelu_sig(float x){
  float u = x*(1.5957691216057308f + 0.07135481627f*x*x);
  return x / (1.0f + expf(-u));
}
__device__ __forceinline__ ushort f2bf_rnd(float f){
  uint u = __float_as_uint(f);
  return (ushort)((u + 0x8000u) >> 16);
}
__device__ __forceinline__ float bf2f(ushort h){
  return __uint_as_float(((uint)h) << 16);
}
__device__ __forceinline__ void split1(float f, ushort& h, ushort& l){
  h = f2bf_rnd(f);
  float fh = bf2f(h);
  l = (ushort)(__float_as_uint(f - fh) >> 16);
}
// async global->LDS 16B/lane; LDS dest = wave-uniform base + lane*16
__device__ __forceinline__ void gl16(void* lds, const void* g){
  __builtin_amdgcn_global_load_lds(
      (const __attribute__((address_space(1))) void*)g,
      (__attribute__((address_space(3))) void*)lds, 16, 0, 0);
}

// ---- ALL weight transforms in one kernel: hi/lo splits, lm bf16, negA ----
// layer-2 w1/w2 are consumed at NT=1 -> skip their lo writes
__global__ __launch_bounds__(256) void k_split_all(
    const float* __restrict__ in_w, const float* __restrict__ out_w,
    const float* __restrict__ w1, const float* __restrict__ w2,
    const float* __restrict__ lm, const float* __restrict__ Alog,
    ushort* __restrict__ wsp, float* __restrict__ negA){
  int g = blockIdx.x*256 + threadIdx.x;
  if (g >= TOT4) return;
  if (g < 2*L4){
    int l = (g < L4) ? 0 : 1;
    int r = g - l*L4;
    const float* src; size_t dh_off, dl_off;
    bool wlo = true;
    if (r < IN4){
      src = in_w + (size_t)l*1048576 + (size_t)r*4;
      dh_off = (size_t)l*LAYER_US + IN_US  + (size_t)r*4;
      dl_off = (size_t)l*LAYER_US + INL_US + (size_t)r*4;
    } else if (r < OUT4){
      int r2 = r - IN4;
      src = out_w + (size_t)l*524288 + (size_t)r2*4;
      dh_off = (size_t)l*LAYER_US + OUT_US  + (size_t)r2*4;
      dl_off = (size_t)l*LAYER_US + OUTL_US + (size_t)r2*4;
    } else if (r < W14){
      int r3 = r - OUT4;
      src = w1 + (size_t)l*8388608 + (size_t)r3*4;
      dh_off = (size_t)l*LAYER_US + W1_US  + (size_t)r3*4;
      dl_off = (size_t)l*LAYER_US + W1L_US + (size_t)r3*4;
      wlo = (l == 0);
    } else {
      int r4 = r - W14;
      src = w2 + (size_t)l*8388608 + (size_t)r4*4;
      dh_off = (size_t)l*LAYER_US + W2_US  + (size_t)r4*4;
      dl_off = (size_t)l*LAYER_US + W2L_US + (size_t)r4*4;
      wlo = (l == 0);
    }
    float4 v = *(const float4*)src;
    ushort h0,h1,h2,h3,l0,l1,l2,l3;
    split1(v.x,h0,l0); split1(v.y,h1,l1); split1(v.z,h2,l2); split1(v.w,h3,l3);
    *(uint2*)(wsp + dh_off) = make_uint2((uint)h0|((uint)h1<<16), (uint)h2|((uint)h3<<16));
    if (wlo)
      *(uint2*)(wsp + dl_off) = make_uint2((uint)l0|((uint)l1<<16), (uint)l2|((uint)l3<<16));
  } else if (g < LMEND){
    int r = g - 2*L4;
    float4 v = *(const float4*)(lm + (size_t)r*4);
    ushort h0 = f2bf_rnd(v.x), h1 = f2bf_rnd(v.y), h2 = f2bf_rnd(v.z), h3 = f2bf_rnd(v.w);
    *(uint2*)(wsp + LM_US + (size_t)r*4) = make_uint2((uint)h0|((uint)h1<<16), (uint)h2|((uint)h3<<16));
  } else {
    int r = g - LMEND;
    float4 v = *(const float4*)(Alog + (size_t)r*4);
    float4 o; o.x=-expf(v.x); o.y=-expf(v.y); o.z=-expf(v.z); o.w=-expf(v.w);
    *(float4*)(negA + (size_t)r*4) = o;
  }
}

// ------- fused embed + rmsnorm -> split (layer 0 entry) -------
__global__ __launch_bounds__(128) void k_embed_rms(const int* __restrict__ ids,
    const float* __restrict__ tok, const float* __restrict__ pos,
    const float* __restrict__ w, float* __restrict__ x,
    ushort* __restrict__ oh, ushort* __restrict__ ol){
  int t = blockIdx.x;
  int d4 = threadIdx.x << 2;
  int s  = t & (S_-1);
  int id = ids[t];
  float4 tv = *(const float4*)(tok + (size_t)id*D_ + d4);
  float4 pv = *(const float4*)(pos + (size_t)s*D_ + d4);
  float4 v; v.x=tv.x+pv.x; v.y=tv.y+pv.y; v.z=tv.z+pv.z; v.w=tv.w+pv.w;
  *(float4*)(x + (size_t)t*D_ + d4) = v;
  float ss = v.x*v.x + v.y*v.y + v.z*v.z + v.w*v.w;
  #pragma unroll
  for (int off=32; off>=1; off>>=1) ss += __shfl_down(ss, off);
  __shared__ float sred[2];
  if ((threadIdx.x & 63) == 0) sred[threadIdx.x >> 6] = ss;
  __syncthreads();
  float total = sred[0] + sred[1];
  float scale = 1.0f / sqrtf(total * (1.0f/D_) + 1e-6f);
  float4 wv = *(const float4*)(w + d4);
  float4 o; o.x=v.x*scale*wv.x; o.y=v.y*scale*wv.y; o.z=v.z*scale*wv.z; o.w=v.w*scale*wv.w;
  ushort h0,h1,h2,h3,l0,l1,l2,l3;
  split1(o.x,h0,l0); split1(o.y,h1,l1); split1(o.z,h2,l2); split1(o.w,h3,l3);
  *(uint2*)(oh + (size_t)t*D_ + d4) = make_uint2((uint)h0|((uint)h1<<16), (uint)h2|((uint)h3<<16));
  *(uint2*)(ol + (size_t)t*D_ + d4) = make_uint2((uint)l0|((uint)l1<<16), (uint)l2|((uint)l3<<16));
}

// ------- rmsnorm -> split hi/lo; optional fused "x += sum_ks(P3[slotA]+P3[slotB])" -------
template<int ADD>
__global__ __launch_bounds__(128) void k_rmsnorm_split(float* __restrict__ x,
    const float* __restrict__ P3, const int* __restrict__ slotmap,
    const float* __restrict__ w, ushort* __restrict__ oh, ushort* __restrict__ ol){
  int t = blockIdx.x;
  int d4 = threadIdx.x << 2;
  float4 v = *(const float4*)(x + (size_t)t*D_ + d4);
  if (ADD){
    int s0 = slotmap[2*t], s1 = slotmap[2*t+1];
    #pragma unroll
    for (int ks=0; ks<4; ++ks){
      float4 p0 = *(const float4*)(P3 + ((size_t)ks*NSLOT + s0)*D_ + d4);
      float4 p1 = *(const float4*)(P3 + ((size_t)ks*NSLOT + s1)*D_ + d4);
      v.x += p0.x + p1.x; v.y += p0.y + p1.y; v.z += p0.z + p1.z; v.w += p0.w + p1.w;
    }
    *(float4*)(x + (size_t)t*D_ + d4) = v;
  }
  float ss = v.x*v.x + v.y*v.y + v.z*v.z + v.w*v.w;
  #pragma unroll
  for (int off=32; off>=1; off>>=1) ss += __shfl_down(ss, off);
  __shared__ float sred[2];
  if ((threadIdx.x & 63) == 0) sred[threadIdx.x >> 6] = ss;
  __syncthreads();
  float total = sred[0] + sred[1];
  float scale = 1.0f / sqrtf(total * (1.0f/D_) + 1e-6f);
  float4 wv = *(const float4*)(w + d4);
  float4 o; o.x=v.x*scale*wv.x; o.y=v.y*scale*wv.y; o.z=v.z*scale*wv.z; o.w=v.w*scale*wv.w;
  ushort h0,h1,h2,h3,l0,l1,l2,l3;
  split1(o.x,h0,l0); split1(o.y,h1,l1); split1(o.z,h2,l2); split1(o.w,h3,l3);
  *(uint2*)(oh + (size_t)t*D_ + d4) = make_uint2((uint)h0|((uint)h1<<16), (uint)h2|((uint)h3<<16));
  *(uint2*)(ol + (size_t)t*D_ + d4) = make_uint2((uint)l0|((uint)l1<<16), (uint)l2|((uint)l3<<16));
}

// ------- fused: x += sum_ks P2; rmsnorm -> split; router probs/top2 -------
__global__ __launch_bounds__(128) void k_rmsnorm_router(float* __restrict__ x,
    const float* __restrict__ P2, const float* __restrict__ w,
    const float* __restrict__ rw, const float* __restrict__ rb,
    ushort* __restrict__ oh, ushort* __restrict__ ol,
    float* __restrict__ probs, float* __restrict__ topw, int* __restrict__ topi){
  int t = blockIdx.x;
  int tid = threadIdx.x;
  int d4 = tid << 2;
  float4 v = *(const float4*)(x + (size_t)t*D_ + d4);
  #pragma unroll
  for (int ks=0; ks<4; ++ks){
    float4 p = *(const float4*)(P2 + (size_t)ks*NTOK*D_ + (size_t)t*D_ + d4);
    v.x += p.x; v.y += p.y; v.z += p.z; v.w += p.w;
  }
  *(float4*)(x + (size_t)t*D_ + d4) = v;
  float ss = v.x*v.x + v.y*v.y + v.z*v.z + v.w*v.w;
  #pragma unroll
  for (int off=32; off>=1; off>>=1) ss += __shfl_down(ss, off);
  __shared__ float sred[2];
  __shared__ float lg2[2][E_];
  __shared__ float lg[E_];
  if ((tid & 63) == 0) sred[tid >> 6] = ss;
  __syncthreads();
  float total = sred[0] + sred[1];
  float scale = 1.0f / sqrtf(total * (1.0f/D_) + 1e-6f);
  float4 wv = *(const float4*)(w + d4);
  float4 o; o.x=v.x*scale*wv.x; o.y=v.y*scale*wv.y; o.z=v.z*scale*wv.z; o.w=v.w*scale*wv.w;
  ushort h0,h1,h2,h3,l0,l1,l2,l3;
  split1(o.x,h0,l0); split1(o.y,h1,l1); split1(o.z,h2,l2); split1(o.w,h3,l3);
  *(uint2*)(oh + (size_t)t*D_ + d4) = make_uint2((uint)h0|((uint)h1<<16), (uint)h2|((uint)h3<<16));
  *(uint2*)(ol + (size_t)t*D_ + d4) = make_uint2((uint)l0|((uint)l1<<16), (uint)l2|((uint)l3<<16));
  int lane = tid & 63, wid2 = tid >> 6;
  #pragma unroll
  for (int e=0;e<E_;e++){
    const float* rr = rw + (size_t)e*D_ + d4;
    float p = o.x*rr[0] + o.y*rr[1] + o.z*rr[2] + o.w*rr[3];
    #pragma unroll
    for (int off=32; off>=1; off>>=1) p += __shfl_down(p, off);
    if (lane==0) lg2[wid2][e] = p;
  }
  __syncthreads();
  if (tid==0){
    #pragma unroll
    for (int e=0;e<E_;e++) lg[e] = lg2[0][e] + lg2[1][e] + rb[e];
    float mx = lg[0];
    #pragma unroll
    for (int e=1;e<E_;e++) mx = fmaxf(mx, lg[e]);
    float pe[E_]; float sum = 0.f;
    #pragma unroll
    for (int e=0;e<E_;e++){ pe[e] = expf(lg[e]-mx); sum += pe[e]; }
    #pragma unroll
    for (int e=0;e<E_;e++){ pe[e] /= sum; probs[(size_t)t*E_ + e] = pe[e]; }
    int i1 = 0;
    #pragma unroll
    for (int e=1;e<E_;e++) if (pe[e] > pe[i1]) i1 = e;
    int i2 = (i1==0) ? 1 : 0;
    #pragma unroll
    for (int e=0;e<E_;e++) if (e!=i1 && pe[e] > pe[i2]) i2 = e;
    float wsum = pe[i1] + pe[i2];
    topw[t*2]   = pe[i1]/wsum;
    topw[t*2+1] = pe[i2]/wsum;
    topi[t*2] = i1; topi[t*2+1] = i2;
  }
}

// ============ split-bf16 MFMA GEMM, global_load_lds staging ============
// MT=128 row tile (proven optimum for this 2-barrier structure; MT=64 regressed
// round-10: W-staging per output doubles, MFMA/barrier halves).
// LDS [rows][32 us] unpadded; 16B chunk g of row r stored at phys g^((r>>1)&3)
// (2-way-only bank aliasing on b128 reads).
template<int EPI, int NT, int KSP, int MT>
__global__ __launch_bounds__(256, 4) void gemm_mfma(
    const ushort* __restrict__ Ahg, const ushort* __restrict__ Alg,
    const ushort* __restrict__ Whb, const ushort* __restrict__ Wlb,
    float* __restrict__ Cb, ushort* __restrict__ Chh, ushort* __restrict__ Chl,
    const float* __restrict__ biasb, const float* __restrict__ slotw,
    const int* __restrict__ gidx, const int* __restrict__ offs,
    int M, int N, int K)
{
  constexpr int MI  = MT/32;    // acc rows (A frags per wave)
  constexpr int AG  = MT/64;    // A staging groups per wave
  constexpr int RPW = MT/4;     // A rows staged per wave
  int e, ksp;
  if (KSP > 1){ e = blockIdx.z / KSP; ksp = blockIdx.z % KSP; }
  else        { e = blockIdx.z;       ksp = 0; }
  int off = 0, cnt = M;
  if (EPI==1 || EPI==3){
    off = offs[e];
    cnt = offs[e+1] - off;
    if ((int)(blockIdx.x*MT) >= cnt) return;
  }
  const size_t wbase = (size_t)((EPI==1||EPI==3) ? e : 0) * N * K;
  const ushort* Whg = Whb + wbase;
  const ushort* Wlg = Wlb + wbase;
  const float* bias = (EPI==1||EPI==3) ? (biasb + (size_t)e * N) : biasb;

  __shared__ ushort sAh[MT*32];
  __shared__ ushort sWh[128*32];
  __shared__ ushort sAl[(NT>1)?(MT*32):8];
  __shared__ ushort sWl[(NT>1)?(128*32):8];

  const int tid  = threadIdx.x;
  const int row0 = blockIdx.x * MT;
  const int col0 = blockIdx.y * 128;
  const int lane = tid & 63;
  const int wid  = tid >> 6;

  const int schunk = (lane&3) ^ ((lane>>3)&3);   // (r>>1)&3 pre-swizzle
  const int arow_b = wid*RPW + (lane>>2);
  const int wrow_b = wid*32  + (lane>>2);

  const int k0 = ksp * (K / KSP);
  const int nk = K / KSP;

  const ushort* gah[2]; const ushort* gal[2];
  #pragma unroll
  for (int s=0; s<AG; ++s){
    int lrr = row0 + arow_b + s*16;
    int ar;
    if (EPI==1){ if (lrr > cnt-1) lrr = cnt-1; ar = gidx[off + lrr]; }
    else if (EPI==3){ if (lrr > cnt-1) lrr = cnt-1; ar = off + lrr; }
    else ar = lrr;
    gah[s] = Ahg + (size_t)ar*K + k0 + schunk*8;
    if (NT>1) gal[s] = Alg + (size_t)ar*K + k0 + schunk*8;
  }
  const ushort* gwh[2]; const ushort* gwl[2];
  #pragma unroll
  for (int s=0; s<2; ++s){
    int wr = col0 + wrow_b + s*16;
    gwh[s] = Whg + (size_t)wr*K + k0 + schunk*8;
    if (NT>1) gwl[s] = Wlg + (size_t)wr*K + k0 + schunk*8;
  }

  const int lr  = lane & 15;
  const int kq  = lane >> 4;
  const int kx  = ((kq ^ ((lr>>1)&3)) << 3);
  const int wrM = (wid >> 1) * (MT/2);
  const int wcN = (wid & 1) * 64;

  f32x4 zero = {0.f, 0.f, 0.f, 0.f};
  f32x4 acc[MI][4];
  #pragma unroll
  for (int i=0;i<MI;i++)
    #pragma unroll
    for (int j=0;j<4;j++) acc[i][j] = zero;

  for (int kk=0; kk<nk; kk+=32){
    __syncthreads();
    #pragma unroll
    for (int s=0; s<AG; ++s)
      gl16(&sAh[(wid*RPW + s*16)*32], gah[s] + kk);
    #pragma unroll
    for (int s=0; s<2; ++s)
      gl16(&sWh[(wid*32 + s*16)*32], gwh[s] + kk);
    if (NT>1){
      #pragma unroll
      for (int s=0; s<AG; ++s)
        gl16(&sAl[(wid*RPW + s*16)*32], gal[s] + kk);
      #pragma unroll
      for (int s=0; s<2; ++s)
        gl16(&sWl[(wid*32 + s*16)*32], gwl[s] + kk);
    }
    __syncthreads();

    short8 fah[MI], fal[MI], fbh[4], fbl[4];
    #pragma unroll
    for (int f=0; f<MI; ++f){
      int rA = wrM + f*16 + lr;
      fah[f] = *(const short8*)&sAh[rA*32 + kx];
      if (NT>1) fal[f] = *(const short8*)&sAl[rA*32 + kx];
    }
    #pragma unroll
    for (int f=0; f<4; ++f){
      int rB = wcN + f*16 + lr;
      fbh[f] = *(const short8*)&sWh[rB*32 + kx];
      if (NT>1) fbl[f] = *(const short8*)&sWl[rB*32 + kx];
    }
    #pragma unroll
    for (int i=0;i<MI;i++)
      #pragma unroll
      for (int j=0;j<4;j++){
        f32x4 c = acc[i][j];
        if (NT==4) c = __builtin_amdgcn_mfma_f32_16x16x32_bf16(fal[i], fbl[j], c, 0,0,0);
        if (NT>1){
          c = __builtin_amdgcn_mfma_f32_16x16x32_bf16(fal[i], fbh[j], c, 0,0,0);
          c = __builtin_amdgcn_mfma_f32_16x16x32_bf16(fah[i], fbl[j], c, 0,0,0);
        }
        c = __builtin_amdgcn_mfma_f32_16x16x32_bf16(fah[i], fbh[j], c, 0,0,0);
        acc[i][j] = c;
      }
  }

  float bj[4];
  if (EPI==1 || EPI==3){
    #pragma unroll
    for (int j=0;j<4;j++) bj[j] = bias[col0 + wcN + j*16 + lr];
  }
  #pragma unroll
  for (int i=0;i<MI;i++){
    #pragma unroll
    for (int jj=0;jj<4;jj++){
      int rt   = wrM + i*16 + kq*4 + jj;
      int grow = row0 + rt;
      if (EPI==0){
        float* cr = Cb + (size_t)grow*N + col0 + wcN + lr;
        #pragma unroll
        for (int j=0;j<4;j++) cr[j*16] = acc[i][j][jj];
      } else if (EPI==2){
        float* cr = Cb + (size_t)ksp*M*N + (size_t)grow*N + col0 + wcN + lr;
        #pragma unroll
        for (int j=0;j<4;j++) cr[j*16] = acc[i][j][jj];
      } else if (EPI==1){
        if (grow < cnt){
          int slot = off + grow;
          size_t base = (size_t)slot*N + col0 + wcN + lr;
          #pragma unroll
          for (int j=0;j<4;j++){
            float g = gelu_sig(acc[i][j][jj] + bj[j]);
            ushort hh_ = f2bf_rnd(g);
            Chh[base + j*16] = hh_;
            if (NT>1){
              ushort ll_ = (ushort)(__float_as_uint(g - bf2f(hh_)) >> 16);
              Chl[base + j*16] = ll_;
            }
          }
        }
      } else {
        if (grow < cnt){
          int slot = off + grow;
          float sw = slotw[slot];
          float* cr = Cb + ((size_t)ksp*NSLOT + slot)*N + col0 + wcN + lr;
          #pragma unroll
          for (int j=0;j<4;j++){
            float v = acc[i][j][jj];
            if (ksp==0) v += bj[j];
            cr[j*16] = sw*v;
          }
        }
      }
    }
  }
}

// ============ lm_head: bf16 GEMM, 128x256 tile, global_load_lds ============
__global__ __launch_bounds__(256, 2) void gemm_lm(
    const ushort* __restrict__ Ahg, const ushort* __restrict__ Whg,
    float* __restrict__ Cb, int M, int N, int K)
{
  __shared__ ushort sAh[128*32];
  __shared__ ushort sWh[256*32];
  const int tid  = threadIdx.x;
  const int row0 = blockIdx.x * 128;
  const int col0 = blockIdx.y * 256;
  const int lane = tid & 63;
  const int wid  = tid >> 6;

  const int schunk = (lane&3) ^ ((lane>>3)&3);
  const int srowA  = wid*32 + (lane>>2);
  const int ldsA0  = (wid*32)*32;
  const int ldsA1  = (wid*32+16)*32;
  const ushort* ga0 = Ahg + (size_t)(row0 + srowA)*K + schunk*8;
  const ushort* ga1 = Ahg + (size_t)(row0 + srowA + 16)*K + schunk*8;

  const int srowW  = wid*64 + (lane>>2);
  const int ldsW0  = (wid*64)*32,    ldsW1 = (wid*64+16)*32;
  const int ldsW2  = (wid*64+32)*32, ldsW3 = (wid*64+48)*32;
  const ushort* gw0 = Whg + (size_t)(col0 + srowW)*K      + schunk*8;
  const ushort* gw1 = Whg + (size_t)(col0 + srowW + 16)*K + schunk*8;
  const ushort* gw2 = Whg + (size_t)(col0 + srowW + 32)*K + schunk*8;
  const ushort* gw3 = Whg + (size_t)(col0 + srowW + 48)*K + schunk*8;

  const int lr  = lane & 15;
  const int kq  = lane >> 4;
  const int kx  = ((kq ^ ((lr>>1)&3)) << 3);
  const int wrM = (wid >> 1) * 64;
  const int wcN = (wid & 1) * 128;

  f32x4 zero = {0.f, 0.f, 0.f, 0.f};
  f32x4 acc[4][8];
  #pragma unroll
  for (int i=0;i<4;i++)
    #pragma unroll
    for (int j=0;j<8;j++) acc[i][j] = zero;

  for (int kk=0; kk<K; kk+=32){
    __syncthreads();
    gl16(&sAh[ldsA0], ga0 + kk);
    gl16(&sAh[ldsA1], ga1 + kk);
    gl16(&sWh[ldsW0], gw0 + kk);
    gl16(&sWh[ldsW1], gw1 + kk);
    gl16(&sWh[ldsW2], gw2 + kk);
    gl16(&sWh[ldsW3], gw3 + kk);
    __syncthreads();

    short8 fa[4], fb[8];
    #pragma unroll
    for (int f=0; f<4; ++f)
      fa[f] = *(const short8*)&sAh[(wrM + f*16 + lr)*32 + kx];
    #pragma unroll
    for (int f=0; f<8; ++f)
      fb[f] = *(const short8*)&sWh[(wcN + f*16 + lr)*32 + kx];
    #pragma unroll
    for (int i=0;i<4;i++)
      #pragma unroll
      for (int j=0;j<8;j++)
        acc[i][j] = __builtin_amdgcn_mfma_f32_16x16x32_bf16(fa[i], fb[j], acc[i][j], 0,0,0);
  }

  #pragma unroll
  for (int i=0;i<4;i++){
    #pragma unroll
    for (int jj=0;jj<4;jj++){
      int grow = row0 + wrM + i*16 + kq*4 + jj;
      float* cr = Cb + (size_t)grow*N + col0 + wcN + lr;
      #pragma unroll
      for (int j=0;j<8;j++) cr[j*16] = acc[i][j][jj];
    }
  }
}

// ------ fused: conv(KC=4)+bias ; x_dbl (B,delta,sdb) ; a,b tensors ------
__global__ __launch_bounds__(256) void k_convab(const float* __restrict__ xz,
    const float* __restrict__ cw, const float* __restrict__ cb,
    const float* __restrict__ xpw, const float* __restrict__ dtw,
    const float* __restrict__ dtb, const float* __restrict__ negA,
    float* __restrict__ a, float* __restrict__ bb){
  int t = blockIdx.x;
  int b = t >> 10, s = t & (S_-1);
  int tid = threadIdx.x;
  int c0 = tid << 2;
  __shared__ float xrow[DI_];
  __shared__ float outv[32];
  __shared__ float dl[DS_+1];
  float4 acc = *(const float4*)(cb + c0);
  #pragma unroll
  for (int k=0;k<KC_;k++){
    int ss = s - (KC_-1) + k;
    if (ss >= 0){
      float4 xv = *(const float4*)(xz + ((size_t)(b*S_+ss))*(2*DI_) + c0);
      acc.x += xv.x * cw[(c0+0)*KC_ + k];
      acc.y += xv.y * cw[(c0+1)*KC_ + k];
      acc.z += xv.z * cw[(c0+2)*KC_ + k];
      acc.w += xv.w * cw[(c0+3)*KC_ + k];
    }
  }
  *(float4*)(xrow + c0) = acc;
  __syncthreads();
  int wid = tid >> 6, lane = tid & 63;
  #pragma unroll
  for (int oi=0; oi<8; ++oi){
    int o = wid*8 + oi;
    const float* wr = (o < 16) ? (xpw + (size_t)(DS_ + o)*DI_) : (dtw + (size_t)(o-16)*DI_);
    float sum = 0.f;
    #pragma unroll
    for (int j=0;j<16;j++) sum += xrow[lane + 64*j] * wr[lane + 64*j];
    #pragma unroll
    for (int off=32; off>=1; off>>=1) sum += __shfl_down(sum, off);
    if (lane == 0) outv[o] = sum;
  }
  __syncthreads();
  if (tid < DS_){
    float d  = outv[16+tid] + dtb[tid];
    float sp = fmaxf(d, 0.f) + log1pf(expf(-fabsf(d)));
    dl[tid] = sp;
    float pr = sp * outv[tid];
    #pragma unroll
    for (int off=8; off>=1; off>>=1) pr += __shfl_down(pr, off);
    if (tid == 0) dl[DS_] = pr;
  }
  __syncthreads();
  float sdbv = dl[DS_];
  float av[4];
  #pragma unroll
  for (int i=0;i<4;i++){
    const float* nA = negA + (size_t)(c0+i)*DS_;
    float sum = 0.f;
    #pragma unroll
    for (int ds=0; ds<DS_; ds++) sum += expf(dl[ds] * nA[ds]);
    av[i] = sum;
  }
  *(float4*)(a + (size_t)t*DI_ + c0) = make_float4(av[0],av[1],av[2],av[3]);
  float4 bv; bv.x=acc.x*sdbv; bv.y=acc.y*sdbv; bv.z=acc.z*sdbv; bv.w=acc.w*sdbv;
  *(float4*)(bb + (size_t)t*DI_ + c0) = bv;
}

__global__ __launch_bounds__(256) void k_scan1(const float* __restrict__ a,
    const float* __restrict__ bb, float* __restrict__ aprod, float* __restrict__ yend){
  int g  = blockIdx.x*256 + threadIdx.x;
  int di = g & (DI_-1);
  int c  = (g >> 10) & (NCHUNK-1);
  int b  = g >> 14;
  float ap = 1.f, y = 0.f;
  size_t base = ((size_t)b*S_ + (size_t)c*CHL)*DI_ + di;
  #pragma unroll 4
  for (int i=0;i<CHL;i++){
    float at = a[base + (size_t)i*DI_], bt = bb[base + (size_t)i*DI_];
    y = at*y + bt; ap *= at;
  }
  aprod[g] = ap; yend[g] = y;
}

__global__ __launch_bounds__(256) void k_scan2(const float* __restrict__ a,
    const float* __restrict__ bb, const float* __restrict__ xz,
    const float* __restrict__ aprod, const float* __restrict__ yend,
    ushort* __restrict__ yh, ushort* __restrict__ yl){
  int g  = blockIdx.x*256 + threadIdx.x;
  int di = g & (DI_-1);
  int c  = (g >> 10) & (NCHUNK-1);
  int b  = g >> 14;
  float y = 0.f;
  for (int j=0;j<c;j++){
    int gg = ((b*NCHUNK + j) << 10) + di;
    y = aprod[gg]*y + yend[gg];
  }
  size_t base = ((size_t)b*S_ + (size_t)c*CHL)*DI_ + di;
  #pragma unroll 4
  for (int i=0;i<CHL;i++){
    float at = a[base + (size_t)i*DI_], bt = bb[base + (size_t)i*DI_];
    y = at*y + bt;
    float z = xz[((size_t)(b*S_ + c*CHL + i))*(2*DI_) + DI_ + di];
    float sil = z / (1.f + expf(-z));
    float v = y * sil;
    ushort hh, ll; split1(v, hh, ll);
    yh[base + (size_t)i*DI_] = hh;
    yl[base + (size_t)i*DI_] = ll;
  }
}

// ------- compaction + aux, LDS-staged (single block, 8 warps = 8 experts) -------
__global__ __launch_bounds__(512) void k_compact_aux(const int* __restrict__ topi,
    const float* __restrict__ topw, const float* __restrict__ probs,
    int* __restrict__ gidx, float* __restrict__ asgw, int* __restrict__ slotmap,
    int* __restrict__ offs, float* __restrict__ dst, int first){
  int tid = threadIdx.x;
  int e = tid >> 6, lane = tid & 63;
  __shared__ unsigned char stop[NTOK*2];
  __shared__ float stw[NTOK*2];
  __shared__ int counts[E_];
  __shared__ float red[8][E_];
  for (int i = tid; i < NTOK*2; i += 512){
    stop[i] = (unsigned char)topi[i];
    stw[i]  = topw[i];
  }
  float ps[E_];
  #pragma unroll
  for (int q=0;q<E_;q++) ps[q]=0.f;
  for (int t = tid; t < NTOK; t += 512){
    float4 p0 = *(const float4*)(probs + (size_t)t*E_);
    float4 p1 = *(const float4*)(probs + (size_t)t*E_ + 4);
    ps[0]+=p0.x; ps[1]+=p0.y; ps[2]+=p0.z; ps[3]+=p0.w;
    ps[4]+=p1.x; ps[5]+=p1.y; ps[6]+=p1.z; ps[7]+=p1.w;
  }
  #pragma unroll
  for (int q=0;q<E_;q++){
    float v = ps[q];
    #pragma unroll
    for (int off=32; off>=1; off>>=1) v += __shfl_down(v, off);
    if (lane==0) red[e][q] = v;
  }
  __syncthreads();
  int cnt = 0;
  for (int c=0; c<NTOK/64; ++c){
    int t = c*64 + lane;
    bool flag = (stop[2*t]==e) || (stop[2*t+1]==e);
    unsigned long long m = __ballot(flag);
    cnt += __popcll(m);
  }
  if (lane==0) counts[e] = cnt;
  __syncthreads();
  int base = 0;
  for (int i=0;i<e;i++) base += counts[i];
  if (lane==0) offs[e] = base;
  if (tid==0){
    int tot=0;
    for (int i=0;i<E_;i++) tot += counts[i];
    offs[E_] = tot;
  }
  int run = base;
  for (int c=0; c<NTOK/64; ++c){
    int t = c*64 + lane;
    int which = (stop[2*t]==e) ? 0 : ((stop[2*t+1]==e) ? 1 : -1);
    bool flag = which >= 0;
    unsigned long long m = __ballot(flag);
    int rank = __popcll(m & ((1ull<<lane)-1ull));
    if (flag){
      int pos = run + rank;
      gidx[pos] = t;
      asgw[pos] = stw[2*t+which];
      slotmap[2*t+which] = pos;
    }
    run += __popcll(m);
  }
  if (tid==0){
    float aux = 0.f;
    #pragma unroll
    for (int i=0;i<E_;i++){
      float P = 0.f;
      #pragma unroll
      for (int wdd=0; wdd<8; ++wdd) P += red[wdd][i];
      P *= (1.0f/NTOK);
      float f = (float)counts[i] * (1.0f/(NTOK*2.0f));
      aux += f*P;
    }
    aux *= (float)E_;
    if (first) dst[0] = aux; else dst[0] += aux;
  }
}

// ---------------- host ----------------
extern "C" void kernel_launch(void* const* d_in, const int* in_sizes, int n_in,
                              void* d_out, int out_size, void* d_ws, size_t ws_size,
                              hipStream_t stream) {
  const int*   input_ids  = (const int*)  d_in[0];
  const float* tok_emb    = (const float*)d_in[1];
  const float* pos_emb    = (const float*)d_in[2];
  const float* norm1_w    = (const float*)d_in[3];
  const float* norm2_w    = (const float*)d_in[4];
  const float* in_proj_w  = (const float*)d_in[5];
  const float* conv_w     = (const float*)d_in[6];
  const float* conv_b     = (const float*)d_in[7];
  const float* x_proj_w   = (const float*)d_in[8];
  const float* dt_proj_w  = (const float*)d_in[9];
  const float* dt_proj_b  = (const float*)d_in[10];
  const float* A_log      = (const float*)d_in[11];
  const float* out_proj_w = (const float*)d_in[13];
  const float* router_w   = (const float*)d_in[14];
  const float* router_b   = (const float*)d_in[15];
  const float* w1         = (const float*)d_in[16];
  const float* b1         = (const float*)d_in[17];
  const float* w2         = (const float*)d_in[18];
  const float* b2         = (const float*)d_in[19];
  const float* final_norm = (const float*)d_in[20];
  const float* lm_head_w  = (const float*)d_in[21];
  float* out = (float*)d_out;

  float* f0 = (float*)d_ws;
  float*  x    = f0;
  ushort* xnh  = (ushort*)(f0 + 1048576);
  ushort* xnl  = xnh + 1048576;
  float*  xz   = f0 + 2097152;
  float*  a    = f0 + 6291456;
  float*  bb   = f0 + 8388608;
  ushort* yh   = (ushort*)(f0 + 10485760);
  ushort* yl   = yh + 2097152;
  ushort* hh   = (ushort*)(f0 + 12582912);
  ushort* hl   = hh + 8388608;
  float*  P2   = f0 + 20971520;
  float*  P3   = f0 + 25165824;
  ushort* wsplit = (ushort*)(f0 + 33554432);
  float*  negA = f0 + 78446592;
  float*  aprod= negA + 32768;
  float*  yendb= aprod + 32768;
  float*  probs= yendb + 32768;
  float*  topw = probs + 16384;
  float*  asgw = topw + 4096;
  int*    topi = (int*)(asgw + 4096);
  int*    gidx = topi + 4096;
  int*    slotmap = gidx + 4096;
  int*    offs = slotmap + 4096;

  float* aux_dst = out + (size_t)NTOK*VOCAB;

  k_split_all<<<(TOT4+255)/256, 256, 0, stream>>>(in_proj_w, out_proj_w, w1, w2,
                                                  lm_head_w, A_log, wsplit, negA);
  k_embed_rms<<<NTOK, 128, 0, stream>>>(input_ids, tok_emb, pos_emb, norm1_w, x, xnh, xnl);

  for (int l=0; l<2; ++l){
    ushort* L = wsplit + (size_t)l*LAYER_US;
    // ---- mamba ----
    if (l == 1)
      k_rmsnorm_split<1><<<NTOK, 128, 0, stream>>>(x, P3, slotmap,
          norm1_w + (size_t)l*D_, xnh, xnl);
    gemm_mfma<0,3,1,128><<<dim3(16,16,1), 256, 0, stream>>>(xnh, xnl, L+IN_US, L+INL_US,
        xz, nullptr, nullptr, nullptr, nullptr, nullptr, nullptr, NTOK, 2*DI_, D_);
    k_convab<<<NTOK, 256, 0, stream>>>(xz, conv_w + (size_t)l*DI_*KC_, conv_b + (size_t)l*DI_,
                                       x_proj_w + (size_t)l*2*DS_*DI_,
                                       dt_proj_w + (size_t)l*DS_*DI_, dt_proj_b + (size_t)l*DS_,
                                       negA + (size_t)l*DI_*DS_, a, bb);
    k_scan1<<<(NTOK*NCHUNK)/256, 256, 0, stream>>>(a, bb, aprod, yendb);
    k_scan2<<<(NTOK*NCHUNK)/256, 256, 0, stream>>>(a, bb, xz, aprod, yendb, yh, yl);
    gemm_mfma<2,3,4,128><<<dim3(16,4,4), 256, 0, stream>>>(yh, yl, L+OUT_US, L+OUTL_US,
        P2, nullptr, nullptr, nullptr, nullptr, nullptr, nullptr, NTOK, D_, DI_);
    // ---- moe (sparse top-2) ----
    k_rmsnorm_router<<<NTOK, 128, 0, stream>>>(x, P2, norm2_w + (size_t)l*D_,
        router_w + (size_t)l*E_*D_, router_b + (size_t)l*E_,
        xnh, xnl, probs, topw, topi);
    k_compact_aux<<<1, 512, 0, stream>>>(topi, topw, probs, gidx, asgw, slotmap, offs,
                                         aux_dst, l==0 ? 1 : 0);
    if (l == 0){
      gemm_mfma<1,3,1,128><<<dim3(16,16,8), 256, 0, stream>>>(xnh, xnl, L+W1_US, L+W1L_US,
          nullptr, hh, hl, b1 + (size_t)l*E_*DFF_, nullptr, gidx, offs, 0, DFF_, D_);
      gemm_mfma<3,3,4,128><<<dim3(16,4,32), 256, 0, stream>>>(hh, hl, L+W2_US, L+W2L_US,
          P3, nullptr, nullptr, b2 + (size_t)l*E_*D_, asgw, gidx, offs, 0, D_, DFF_);
    } else {
      gemm_mfma<1,1,1,128><<<dim3(16,16,8), 256, 0, stream>>>(xnh, nullptr, L+W1_US, nullptr,
          nullptr, hh, nullptr, b1 + (size_t)l*E_*DFF_, nullptr, gidx, offs, 0, DFF_, D_);
      gemm_mfma<3,1,4,128><<<dim3(16,4,32), 256, 0, stream>>>(hh, nullptr, L+W2_US, nullptr,
          P3, nullptr, nullptr, b2 + (size_t)l*E_*D_, asgw, gidx, offs, 0, D_, DFF_);
    }
  }

  // ---- head ----
  k_rmsnorm_split<1><<<NTOK, 128, 0, stream>>>(x, P3, slotmap, final_norm, xnh, xnl);
  gemm_lm<<<dim3(16,125,1), 256, 0, stream>>>(xnh, wsplit + LM_US, out, NTOK, VOCAB, D_);
}